// Round 1
// baseline (224.581 us; speedup 1.0000x reference)
//
#include <hip/hip_runtime.h>
#include <math.h>

namespace {
constexpr int B = 32, C = 2, T = 262144, K = 6;
constexpr int SEG = 512;          // segments per (b,c)
constexpr int L = T / SEG;        // 512 samples per segment
constexpr int NBC = B * C;        // 64 sequences
constexpr int NST = 2 * K;        // 12-dim cascade state
constexpr int LOG2L = 9;          // L = 2^9
constexpr float FS = 44100.0f;
}

// K1: RBJ peaking-EQ coefficients, normalized by a0. cf[(b*K+k)*5 + {b0,b1,b2,a1,a2}]
__global__ void eq_coeffs(const float* __restrict__ fr, const float* __restrict__ gn,
                          const float* __restrict__ qf, float* __restrict__ cf) {
  int i = blockIdx.x * blockDim.x + threadIdx.x;
  if (i >= B * K) return;
  float f = fr[i], g = gn[i], Q = qf[i];
  float A  = powf(10.0f, g * (1.0f / 40.0f));
  float w0 = 6.283185307179586f * f / FS;
  float cw = cosf(w0);
  float al = sinf(w0) / (2.0f * Q);
  float b0 = 1.0f + al * A;
  float b1 = -2.0f * cw;
  float b2 = 1.0f - al * A;
  float a0 = 1.0f + al / A;
  float a2 = 1.0f - al / A;
  float ia = 1.0f / a0;
  float* p = cf + i * 5;
  p[0] = b0 * ia; p[1] = b1 * ia; p[2] = b2 * ia; p[3] = b1 * ia; p[4] = a2 * ia;
}

// Pass over segments. WRITE_OUT=false: zero-state run, record final 12-dim state.
// WRITE_OUT=true: run from exact incoming state, write output.
template <bool WRITE_OUT>
__global__ __launch_bounds__(256) void eq_pass(const float* __restrict__ x,
                                               const float* __restrict__ cf,
                                               const float* __restrict__ st_in,
                                               float* __restrict__ st_out,
                                               float* __restrict__ y) {
  int tid = blockIdx.x * blockDim.x + threadIdx.x;  // [0, NBC*SEG)
  int bc = tid / SEG, seg = tid % SEG;
  int b = bc / C;

  float b0[K], b1[K], b2[K], a1[K], a2[K];
#pragma unroll
  for (int k = 0; k < K; ++k) {
    const float* p = cf + (b * K + k) * 5;
    b0[k] = p[0]; b1[k] = p[1]; b2[k] = p[2]; a1[k] = p[3]; a2[k] = p[4];
  }

  float s1[K], s2[K];
  if (WRITE_OUT) {
    const float4* si = reinterpret_cast<const float4*>(st_in + (size_t)tid * NST);
    float4 v0 = si[0], v1 = si[1], v2 = si[2];
    s1[0] = v0.x; s2[0] = v0.y; s1[1] = v0.z; s2[1] = v0.w;
    s1[2] = v1.x; s2[2] = v1.y; s1[3] = v1.z; s2[3] = v1.w;
    s1[4] = v2.x; s2[4] = v2.y; s1[5] = v2.z; s2[5] = v2.w;
  } else {
#pragma unroll
    for (int k = 0; k < K; ++k) { s1[k] = 0.0f; s2[k] = 0.0f; }
  }

  const float* xp = x + (size_t)bc * T + (size_t)seg * L;
  float* yp = y + (size_t)bc * T + (size_t)seg * L;

  for (int t = 0; t < L; t += 4) {
    float4 v = *reinterpret_cast<const float4*>(xp + t);
    float in4[4] = {v.x, v.y, v.z, v.w};
    float out4[4];
#pragma unroll
    for (int j = 0; j < 4; ++j) {
      float yv = in4[j];
#pragma unroll
      for (int k = 0; k < K; ++k) {
        float yk = fmaf(b0[k], yv, s1[k]);
        float t1 = fmaf(b1[k], yv, s2[k]);
        s1[k] = fmaf(-a1[k], yk, t1);
        float t2 = b2[k] * yv;
        s2[k] = fmaf(-a2[k], yk, t2);
        yv = yk;
      }
      out4[j] = yv;
    }
    if (WRITE_OUT) {
      *reinterpret_cast<float4*>(yp + t) =
          make_float4(out4[0], out4[1], out4[2], out4[3]);
    }
  }

  if (!WRITE_OUT) {
    float4* so = reinterpret_cast<float4*>(st_out + (size_t)tid * NST);
    so[0] = make_float4(s1[0], s2[0], s1[1], s2[1]);
    so[1] = make_float4(s1[2], s2[2], s1[3], s2[3]);
    so[2] = make_float4(s1[4], s2[4], s1[5], s2[5]);
  }
}

// K3: per (b,c), build Phi = A^L via repeated squaring (12 lanes hold columns),
// then sequential affine scan over segments: s[i+1] = Phi*s[i] + zsf[i].
// Emits incoming state per segment.
__global__ __launch_bounds__(64) void eq_scan(const float* __restrict__ cf,
                                              const float* __restrict__ zsf,
                                              float* __restrict__ sif) {
  int bc = blockIdx.x;
  int b = bc / C;
  int l = threadIdx.x;

  float b0[K], b1[K], b2[K], a1[K], a2[K];
#pragma unroll
  for (int k = 0; k < K; ++k) {
    const float* p = cf + (b * K + k) * 5;
    b0[k] = p[0]; b1[k] = p[1]; b2[k] = p[2]; a1[k] = p[3]; a2[k] = p[4];
  }

  // column l of one-sample homogeneous map A (input x = 0, state = e_l)
  float col[NST];
  {
    float s1[K], s2[K];
#pragma unroll
    for (int k = 0; k < K; ++k) {
      s1[k] = (l == 2 * k) ? 1.0f : 0.0f;
      s2[k] = (l == 2 * k + 1) ? 1.0f : 0.0f;
    }
    float yv = 0.0f;
#pragma unroll
    for (int k = 0; k < K; ++k) {
      float yk = fmaf(b0[k], yv, s1[k]);
      float t1 = fmaf(b1[k], yv, s2[k]);
      float ns1 = fmaf(-a1[k], yk, t1);
      float ns2 = fmaf(-a2[k], yk, b2[k] * yv);
      s1[k] = ns1; s2[k] = ns2; yv = yk;
    }
#pragma unroll
    for (int k = 0; k < K; ++k) { col[2 * k] = s1[k]; col[2 * k + 1] = s2[k]; }
  }

  // Phi = A^(2^LOG2L): lane l holds column l; squaring: col_l' = sum_m col_m * M[m][l]
  for (int p = 0; p < LOG2L; ++p) {
    float nc[NST];
#pragma unroll
    for (int r = 0; r < NST; ++r) nc[r] = 0.0f;
#pragma unroll
    for (int m = 0; m < NST; ++m) {
      float w = col[m];  // M[m][l], local
#pragma unroll
      for (int r = 0; r < NST; ++r) {
        float cmr = __shfl(col[r], m);  // M[r][m] from lane m
        nc[r] = fmaf(cmr, w, nc[r]);
      }
    }
#pragma unroll
    for (int r = 0; r < NST; ++r) col[r] = nc[r];
  }

  // transpose columns -> rows (lane l keeps row l for the mat-vec)
  __shared__ float M[NST][NST];
  if (l < NST) {
#pragma unroll
    for (int r = 0; r < NST; ++r) M[r][l] = col[r];
  }
  __syncthreads();
  float row[NST];
#pragma unroll
  for (int m = 0; m < NST; ++m) row[m] = (l < NST) ? M[l][m] : 0.0f;

  // affine scan over SEG segments; lane l carries state component l
  const float* z = zsf + (size_t)bc * SEG * NST;
  float* o = sif + (size_t)bc * SEG * NST;
  float s = 0.0f;
  for (int i = 0; i < SEG; ++i) {
    if (l < NST) o[(size_t)i * NST + l] = s;  // incoming state of segment i
    float zv = (l < NST) ? z[(size_t)i * NST + l] : 0.0f;
    float a0a = 0.0f, a1a = 0.0f, a2a = 0.0f;
#pragma unroll
    for (int m = 0; m < NST; m += 3) {
      a0a = fmaf(row[m],     __shfl(s, m),     a0a);
      a1a = fmaf(row[m + 1], __shfl(s, m + 1), a1a);
      a2a = fmaf(row[m + 2], __shfl(s, m + 2), a2a);
    }
    s = ((a0a + a1a) + a2a) + zv;
  }
}

extern "C" void kernel_launch(void* const* d_in, const int* in_sizes, int n_in,
                              void* d_out, int out_size, void* d_ws, size_t ws_size,
                              hipStream_t stream) {
  const float* audio = (const float*)d_in[0];
  const float* fr    = (const float*)d_in[1];
  const float* gn    = (const float*)d_in[2];
  const float* qf    = (const float*)d_in[3];
  float* out = (float*)d_out;

  // ws layout (floats): coeffs | zero-state finals | incoming states
  float* cf  = (float*)d_ws;                 // B*K*5 = 960
  float* zsf = cf + B * K * 5;               // NBC*SEG*NST = 393216
  float* sif = zsf + (size_t)NBC * SEG * NST;  // 393216

  hipLaunchKernelGGL(eq_coeffs, dim3((B * K + 63) / 64), dim3(64), 0, stream,
                     fr, gn, qf, cf);
  hipLaunchKernelGGL((eq_pass<false>), dim3(NBC * SEG / 256), dim3(256), 0, stream,
                     audio, cf, nullptr, zsf, out);
  hipLaunchKernelGGL(eq_scan, dim3(NBC), dim3(64), 0, stream, cf, zsf, sif);
  hipLaunchKernelGGL((eq_pass<true>), dim3(NBC * SEG / 256), dim3(256), 0, stream,
                     audio, cf, sif, nullptr, out);
}

// Round 2
// 148.731 us; speedup vs baseline: 1.5100x; 1.5100x over previous
//
#include <hip/hip_runtime.h>
#include <math.h>

namespace {
constexpr int B = 32, C = 2, T = 262144, K = 6;
constexpr int SEG = 512;          // segments per (b,c)
constexpr int L = T / SEG;        // 512 samples per segment
constexpr int NBC = B * C;        // 64 sequences
constexpr int NST = 2 * K;        // 12-dim cascade state
constexpr int LOG2L = 9;          // L = 2^9
constexpr float FS = 44100.0f;
}

__device__ __forceinline__ float rl(float v, int lane) {
  return __int_as_float(__builtin_amdgcn_readlane(__float_as_int(v), lane));
}

// K1: RBJ peaking-EQ coefficients, normalized by a0. cf[(b*K+k)*5 + {b0,b1,b2,a1,a2}]
__global__ void eq_coeffs(const float* __restrict__ fr, const float* __restrict__ gn,
                          const float* __restrict__ qf, float* __restrict__ cf) {
  int i = blockIdx.x * blockDim.x + threadIdx.x;
  if (i >= B * K) return;
  float f = fr[i], g = gn[i], Q = qf[i];
  float A  = powf(10.0f, g * (1.0f / 40.0f));
  float w0 = 6.283185307179586f * f / FS;
  float cw = cosf(w0);
  float al = sinf(w0) / (2.0f * Q);
  float b0 = 1.0f + al * A;
  float b1 = -2.0f * cw;
  float b2 = 1.0f - al * A;
  float a0 = 1.0f + al / A;
  float a2 = 1.0f - al / A;
  float ia = 1.0f / a0;
  float* p = cf + i * 5;
  p[0] = b0 * ia; p[1] = b1 * ia; p[2] = b2 * ia; p[3] = b1 * ia; p[4] = a2 * ia;
}

// Pass over segments, software-pipelined (4 float4 loads in flight).
// WRITE_OUT=false: zero-state run, record final 12-dim state.
// WRITE_OUT=true: run from exact incoming state, write output.
template <bool WRITE_OUT>
__global__ __launch_bounds__(256) void eq_pass(const float* __restrict__ x,
                                               const float* __restrict__ cf,
                                               const float* __restrict__ st_in,
                                               float* __restrict__ st_out,
                                               float* __restrict__ y) {
  int tid = blockIdx.x * blockDim.x + threadIdx.x;  // [0, NBC*SEG)
  int bc = tid / SEG, seg = tid % SEG;
  int b = bc / C;

  float b0[K], b1[K], b2[K], a1[K], a2[K];
#pragma unroll
  for (int k = 0; k < K; ++k) {
    const float* p = cf + (b * K + k) * 5;
    b0[k] = p[0]; b1[k] = p[1]; b2[k] = p[2]; a1[k] = p[3]; a2[k] = p[4];
  }

  float s1[K], s2[K];
  if (WRITE_OUT) {
    const float4* si = reinterpret_cast<const float4*>(st_in + (size_t)tid * NST);
    float4 v0 = si[0], v1 = si[1], v2 = si[2];
    s1[0] = v0.x; s2[0] = v0.y; s1[1] = v0.z; s2[1] = v0.w;
    s1[2] = v1.x; s2[2] = v1.y; s1[3] = v1.z; s2[3] = v1.w;
    s1[4] = v2.x; s2[4] = v2.y; s1[5] = v2.z; s2[5] = v2.w;
  } else {
#pragma unroll
    for (int k = 0; k < K; ++k) { s1[k] = 0.0f; s2[k] = 0.0f; }
  }

  const float4* xp4 = reinterpret_cast<const float4*>(x + (size_t)bc * T + (size_t)seg * L);
  float4* yp4 = reinterpret_cast<float4*>(y + (size_t)bc * T + (size_t)seg * L);
  constexpr int NV = L / 4;  // 128 float4 loads

  float4 buf[4];
#pragma unroll
  for (int j = 0; j < 4; ++j) buf[j] = xp4[j];

  for (int v = 0; v < NV; v += 4) {
    float4 nbuf[4];
    bool more = (v + 4 < NV);
    if (more) {
#pragma unroll
      for (int j = 0; j < 4; ++j) nbuf[j] = xp4[v + 4 + j];
    }
#pragma unroll
    for (int j = 0; j < 4; ++j) {
      float in4[4] = {buf[j].x, buf[j].y, buf[j].z, buf[j].w};
      float out4[4];
#pragma unroll
      for (int jj = 0; jj < 4; ++jj) {
        float yv = in4[jj];
#pragma unroll
        for (int k = 0; k < K; ++k) {
          float yk = fmaf(b0[k], yv, s1[k]);
          float t1 = fmaf(b1[k], yv, s2[k]);
          s1[k] = fmaf(-a1[k], yk, t1);
          float t2 = b2[k] * yv;
          s2[k] = fmaf(-a2[k], yk, t2);
          yv = yk;
        }
        out4[jj] = yv;
      }
      if (WRITE_OUT) {
        yp4[v + j] = make_float4(out4[0], out4[1], out4[2], out4[3]);
      }
    }
    if (more) {
#pragma unroll
      for (int j = 0; j < 4; ++j) buf[j] = nbuf[j];
    }
  }

  if (!WRITE_OUT) {
    float4* so = reinterpret_cast<float4*>(st_out + (size_t)tid * NST);
    so[0] = make_float4(s1[0], s2[0], s1[1], s2[1]);
    so[1] = make_float4(s1[2], s2[2], s1[3], s2[3]);
    so[2] = make_float4(s1[4], s2[4], s1[5], s2[5]);
  }
}

// K3: per (b,c), build Phi = A^L via repeated squaring (12 lanes hold columns,
// readlane broadcasts), then sequential affine scan over segments with
// chunk-prefetched z: s[i+1] = Phi*s[i] + zsf[i]. Emits incoming state per segment.
__global__ __launch_bounds__(64) void eq_scan(const float* __restrict__ cf,
                                              const float* __restrict__ zsf,
                                              float* __restrict__ sif) {
  int bc = blockIdx.x;
  int b = bc / C;
  int l = threadIdx.x;
  bool act = (l < NST);

  float b0[K], b1[K], b2[K], a1[K], a2[K];
#pragma unroll
  for (int k = 0; k < K; ++k) {
    const float* p = cf + (b * K + k) * 5;
    b0[k] = p[0]; b1[k] = p[1]; b2[k] = p[2]; a1[k] = p[3]; a2[k] = p[4];
  }

  // column l of one-sample homogeneous map A (input x = 0, state = e_l)
  float col[NST];
  {
    float s1[K], s2[K];
#pragma unroll
    for (int k = 0; k < K; ++k) {
      s1[k] = (l == 2 * k) ? 1.0f : 0.0f;
      s2[k] = (l == 2 * k + 1) ? 1.0f : 0.0f;
    }
    float yv = 0.0f;
#pragma unroll
    for (int k = 0; k < K; ++k) {
      float yk = fmaf(b0[k], yv, s1[k]);
      float t1 = fmaf(b1[k], yv, s2[k]);
      float ns1 = fmaf(-a1[k], yk, t1);
      float ns2 = fmaf(-a2[k], yk, b2[k] * yv);
      s1[k] = ns1; s2[k] = ns2; yv = yk;
    }
#pragma unroll
    for (int k = 0; k < K; ++k) { col[2 * k] = s1[k]; col[2 * k + 1] = s2[k]; }
  }

  // Phi = A^(2^LOG2L): lane l holds column l; squaring via readlane broadcast:
  // col_l' = sum_m col_m * M[m][l]  with M[r][m] = (col[r] at lane m)
  for (int p = 0; p < LOG2L; ++p) {
    float nc[NST];
#pragma unroll
    for (int r = 0; r < NST; ++r) nc[r] = 0.0f;
#pragma unroll
    for (int m = 0; m < NST; ++m) {
      float w = col[m];  // M[m][l], local
#pragma unroll
      for (int r = 0; r < NST; ++r) {
        nc[r] = fmaf(rl(col[r], m), w, nc[r]);
      }
    }
#pragma unroll
    for (int r = 0; r < NST; ++r) col[r] = nc[r];
  }

  // transpose columns -> rows (lane l keeps row l for the mat-vec)
  __shared__ float M[NST][NST];
  if (act) {
#pragma unroll
    for (int r = 0; r < NST; ++r) M[r][l] = col[r];
  }
  __syncthreads();
  float row[NST];
#pragma unroll
  for (int m = 0; m < NST; ++m) row[m] = act ? M[l][m] : 0.0f;

  // affine scan; lane l carries state component l. z prefetched per 16-chunk.
  const float* z = zsf + (size_t)bc * SEG * NST;
  float* o = sif + (size_t)bc * SEG * NST;
  float s = 0.0f;
  constexpr int CH = 16;
  for (int i0 = 0; i0 < SEG; i0 += CH) {
    float zb[CH];
#pragma unroll
    for (int j = 0; j < CH; ++j) {
      zb[j] = act ? z[(size_t)(i0 + j) * NST + l] : 0.0f;
    }
#pragma unroll
    for (int j = 0; j < CH; ++j) {
      if (act) o[(size_t)(i0 + j) * NST + l] = s;  // incoming state of segment i0+j
      float t0 = fmaf(row[0], rl(s, 0), fmaf(row[1], rl(s, 1), row[2] * rl(s, 2)));
      float t1 = fmaf(row[3], rl(s, 3), fmaf(row[4], rl(s, 4), row[5] * rl(s, 5)));
      float t2 = fmaf(row[6], rl(s, 6), fmaf(row[7], rl(s, 7), row[8] * rl(s, 8)));
      float t3 = fmaf(row[9], rl(s, 9), fmaf(row[10], rl(s, 10), row[11] * rl(s, 11)));
      s = ((t0 + t1) + (t2 + t3)) + zb[j];
    }
  }
}

extern "C" void kernel_launch(void* const* d_in, const int* in_sizes, int n_in,
                              void* d_out, int out_size, void* d_ws, size_t ws_size,
                              hipStream_t stream) {
  const float* audio = (const float*)d_in[0];
  const float* fr    = (const float*)d_in[1];
  const float* gn    = (const float*)d_in[2];
  const float* qf    = (const float*)d_in[3];
  float* out = (float*)d_out;

  // ws layout (floats): coeffs | zero-state finals | incoming states
  float* cf  = (float*)d_ws;                 // B*K*5 = 960
  float* zsf = cf + B * K * 5;               // NBC*SEG*NST = 393216
  float* sif = zsf + (size_t)NBC * SEG * NST;  // 393216

  hipLaunchKernelGGL(eq_coeffs, dim3((B * K + 63) / 64), dim3(64), 0, stream,
                     fr, gn, qf, cf);
  hipLaunchKernelGGL((eq_pass<false>), dim3(NBC * SEG / 256), dim3(256), 0, stream,
                     audio, cf, nullptr, zsf, out);
  hipLaunchKernelGGL(eq_scan, dim3(NBC), dim3(64), 0, stream, cf, zsf, sif);
  hipLaunchKernelGGL((eq_pass<true>), dim3(NBC * SEG / 256), dim3(256), 0, stream,
                     audio, cf, sif, nullptr, out);
}

// Round 3
// 134.977 us; speedup vs baseline: 1.6638x; 1.1019x over previous
//
#include <hip/hip_runtime.h>
#include <math.h>

namespace {
constexpr int B = 32, C = 2, T = 262144, K = 6;
constexpr int SEG = 512;          // segments per (b,c)
constexpr int L = T / SEG;        // 512 samples per segment
constexpr int NBC = B * C;        // 64 sequences
constexpr int NST = 2 * K;        // 12-dim cascade state
constexpr int LOG2L = 9;          // L = 2^9
constexpr int TS = 16;            // samples per staging tile
constexpr int NT = L / TS;        // 32 tiles
constexpr int WPB = SEG / 64;     // 1-wave blocks per (b,c) = 8
constexpr float FS = 44100.0f;
}

__device__ __forceinline__ float rl(float v, int lane) {
  return __int_as_float(__builtin_amdgcn_readlane(__float_as_int(v), lane));
}

// K1: RBJ peaking-EQ coefficients, normalized by a0. cf[(b*K+k)*5 + {b0,b1,b2,a1,a2}]
__global__ void eq_coeffs(const float* __restrict__ fr, const float* __restrict__ gn,
                          const float* __restrict__ qf, float* __restrict__ cf) {
  int i = blockIdx.x * blockDim.x + threadIdx.x;
  if (i >= B * K) return;
  float f = fr[i], g = gn[i], Q = qf[i];
  float A  = powf(10.0f, g * (1.0f / 40.0f));
  float w0 = 6.283185307179586f * f / FS;
  float cw = cosf(w0);
  float al = sinf(w0) / (2.0f * Q);
  float b0 = 1.0f + al * A;
  float b1 = -2.0f * cw;
  float b2 = 1.0f - al * A;
  float a0 = 1.0f + al / A;
  float a2 = 1.0f - al / A;
  float ia = 1.0f / a0;
  float* p = cf + i * 5;
  p[0] = b0 * ia; p[1] = b1 * ia; p[2] = b2 * ia; p[3] = b1 * ia; p[4] = a2 * ia;
}

// Segment pass, 1 wave per block, LDS transpose-staged I/O.
// Lane l owns segment (segbase + l). Tiles of 16 samples:
//  - cooperative load: 4-lane groups fetch full 64B lines (16 lines/instr, all used)
//  - padded LDS [64][17]: per-lane sequential reads conflict-free
//  - WRITE_OUT: outputs staged to LDS, flushed as full 64B lines.
template <bool WRITE_OUT>
__global__ __launch_bounds__(64) void eq_pass(const float* __restrict__ x,
                                              const float* __restrict__ cf,
                                              const float* __restrict__ st_in,
                                              float* __restrict__ st_out,
                                              float* __restrict__ y) {
  __shared__ float sIn[2][64][17];
  __shared__ float sOut[2][64][17];

  int l = threadIdx.x;
  int wid = blockIdx.x;           // 0 .. NBC*WPB-1
  int bc = wid / WPB;
  int segbase = (wid % WPB) * 64;
  int b = bc / C;
  int tid = bc * SEG + segbase + l;

  float b0[K], b1[K], b2[K], a1[K], a2[K];
#pragma unroll
  for (int k = 0; k < K; ++k) {
    const float* p = cf + (b * K + k) * 5;
    b0[k] = p[0]; b1[k] = p[1]; b2[k] = p[2]; a1[k] = p[3]; a2[k] = p[4];
  }

  float s1[K], s2[K];
  if (WRITE_OUT) {
    const float4* si = reinterpret_cast<const float4*>(st_in + (size_t)tid * NST);
    float4 v0 = si[0], v1 = si[1], v2 = si[2];
    s1[0] = v0.x; s2[0] = v0.y; s1[1] = v0.z; s2[1] = v0.w;
    s1[2] = v1.x; s2[2] = v1.y; s1[3] = v1.z; s2[3] = v1.w;
    s1[4] = v2.x; s2[4] = v2.y; s1[5] = v2.z; s2[5] = v2.w;
  } else {
#pragma unroll
    for (int k = 0; k < K; ++k) { s1[k] = 0.0f; s2[k] = 0.0f; }
  }

  const float4* xp4 = reinterpret_cast<const float4*>(x + (size_t)bc * T + (size_t)segbase * L);
  float4* yp4 = reinterpret_cast<float4*>(y + (size_t)bc * T + (size_t)segbase * L);

  int sj = l >> 2;   // staging sub-segment 0..15
  int qj = l & 3;    // 16B quarter of the 64B line

  // prologue: tile 0 in flight
  float4 r[4];
#pragma unroll
  for (int j = 0; j < 4; ++j)
    r[j] = xp4[(size_t)(j * 16 + sj) * (L / 4) + qj];

  for (int t = 0; t < NT; ++t) {
    int pb = t & 1;
    // stage tile t (regs -> LDS, transposed)
#pragma unroll
    for (int j = 0; j < 4; ++j) {
      int seg = j * 16 + sj;
      sIn[pb][seg][qj * 4 + 0] = r[j].x;
      sIn[pb][seg][qj * 4 + 1] = r[j].y;
      sIn[pb][seg][qj * 4 + 2] = r[j].z;
      sIn[pb][seg][qj * 4 + 3] = r[j].w;
    }
    // prefetch tile t+1 (lands while we compute tile t)
    if (t + 1 < NT) {
#pragma unroll
      for (int j = 0; j < 4; ++j)
        r[j] = xp4[(size_t)(j * 16 + sj) * (L / 4) + (size_t)(t + 1) * 4 + qj];
    }
    // own segment: 16 sequential samples through the 6-stage cascade
    float out16[TS];
#pragma unroll
    for (int i = 0; i < TS; ++i) {
      float yv = sIn[pb][l][i];
#pragma unroll
      for (int k = 0; k < K; ++k) {
        float yk = fmaf(b0[k], yv, s1[k]);
        float t1 = fmaf(b1[k], yv, s2[k]);
        s1[k] = fmaf(-a1[k], yk, t1);
        float t2 = b2[k] * yv;
        s2[k] = fmaf(-a2[k], yk, t2);
        yv = yk;
      }
      out16[i] = yv;
    }
    if (WRITE_OUT) {
#pragma unroll
      for (int i = 0; i < TS; ++i) sOut[pb][l][i] = out16[i];
      // flush as full 64B lines
#pragma unroll
      for (int j = 0; j < 4; ++j) {
        int seg = j * 16 + sj;
        float4 o;
        o.x = sOut[pb][seg][qj * 4 + 0];
        o.y = sOut[pb][seg][qj * 4 + 1];
        o.z = sOut[pb][seg][qj * 4 + 2];
        o.w = sOut[pb][seg][qj * 4 + 3];
        yp4[(size_t)seg * (L / 4) + (size_t)t * 4 + qj] = o;
      }
    }
  }

  if (!WRITE_OUT) {
    float4* so = reinterpret_cast<float4*>(st_out + (size_t)tid * NST);
    so[0] = make_float4(s1[0], s2[0], s1[1], s2[1]);
    so[1] = make_float4(s1[2], s2[2], s1[3], s2[3]);
    so[2] = make_float4(s1[4], s2[4], s1[5], s2[5]);
  }
}

// K3: per (b,c), Phi = A^L via repeated squaring (12 lanes hold columns,
// readlane broadcasts), then sequential affine scan with chunk-prefetched z.
__global__ __launch_bounds__(64) void eq_scan(const float* __restrict__ cf,
                                              const float* __restrict__ zsf,
                                              float* __restrict__ sif) {
  int bc = blockIdx.x;
  int b = bc / C;
  int l = threadIdx.x;
  bool act = (l < NST);

  float b0[K], b1[K], b2[K], a1[K], a2[K];
#pragma unroll
  for (int k = 0; k < K; ++k) {
    const float* p = cf + (b * K + k) * 5;
    b0[k] = p[0]; b1[k] = p[1]; b2[k] = p[2]; a1[k] = p[3]; a2[k] = p[4];
  }

  // column l of the one-sample homogeneous map A
  float col[NST];
  {
    float s1[K], s2[K];
#pragma unroll
    for (int k = 0; k < K; ++k) {
      s1[k] = (l == 2 * k) ? 1.0f : 0.0f;
      s2[k] = (l == 2 * k + 1) ? 1.0f : 0.0f;
    }
    float yv = 0.0f;
#pragma unroll
    for (int k = 0; k < K; ++k) {
      float yk = fmaf(b0[k], yv, s1[k]);
      float t1 = fmaf(b1[k], yv, s2[k]);
      float ns1 = fmaf(-a1[k], yk, t1);
      float ns2 = fmaf(-a2[k], yk, b2[k] * yv);
      s1[k] = ns1; s2[k] = ns2; yv = yk;
    }
#pragma unroll
    for (int k = 0; k < K; ++k) { col[2 * k] = s1[k]; col[2 * k + 1] = s2[k]; }
  }

  // Phi = A^(2^LOG2L) by repeated squaring; lane l holds column l
  for (int p = 0; p < LOG2L; ++p) {
    float nc[NST];
#pragma unroll
    for (int r = 0; r < NST; ++r) nc[r] = 0.0f;
#pragma unroll
    for (int m = 0; m < NST; ++m) {
      float w = col[m];
#pragma unroll
      for (int r = 0; r < NST; ++r) {
        nc[r] = fmaf(rl(col[r], m), w, nc[r]);
      }
    }
#pragma unroll
    for (int r = 0; r < NST; ++r) col[r] = nc[r];
  }

  // transpose columns -> rows
  __shared__ float M[NST][NST];
  if (act) {
#pragma unroll
    for (int r = 0; r < NST; ++r) M[r][l] = col[r];
  }
  __syncthreads();
  float row[NST];
#pragma unroll
  for (int m = 0; m < NST; ++m) row[m] = act ? M[l][m] : 0.0f;

  // affine scan; lane l carries state component l; z prefetched per 16-chunk
  const float* z = zsf + (size_t)bc * SEG * NST;
  float* o = sif + (size_t)bc * SEG * NST;
  float s = 0.0f;
  constexpr int CH = 16;
  for (int i0 = 0; i0 < SEG; i0 += CH) {
    float zb[CH];
#pragma unroll
    for (int j = 0; j < CH; ++j) {
      zb[j] = act ? z[(size_t)(i0 + j) * NST + l] : 0.0f;
    }
#pragma unroll
    for (int j = 0; j < CH; ++j) {
      if (act) o[(size_t)(i0 + j) * NST + l] = s;
      float t0 = fmaf(row[0], rl(s, 0), fmaf(row[1], rl(s, 1), row[2] * rl(s, 2)));
      float t1 = fmaf(row[3], rl(s, 3), fmaf(row[4], rl(s, 4), row[5] * rl(s, 5)));
      float t2 = fmaf(row[6], rl(s, 6), fmaf(row[7], rl(s, 7), row[8] * rl(s, 8)));
      float t3 = fmaf(row[9], rl(s, 9), fmaf(row[10], rl(s, 10), row[11] * rl(s, 11)));
      s = ((t0 + t1) + (t2 + t3)) + zb[j];
    }
  }
}

extern "C" void kernel_launch(void* const* d_in, const int* in_sizes, int n_in,
                              void* d_out, int out_size, void* d_ws, size_t ws_size,
                              hipStream_t stream) {
  const float* audio = (const float*)d_in[0];
  const float* fr    = (const float*)d_in[1];
  const float* gn    = (const float*)d_in[2];
  const float* qf    = (const float*)d_in[3];
  float* out = (float*)d_out;

  // ws layout (floats): coeffs | zero-state finals | incoming states
  float* cf  = (float*)d_ws;                 // B*K*5 = 960
  float* zsf = cf + B * K * 5;               // NBC*SEG*NST = 393216
  float* sif = zsf + (size_t)NBC * SEG * NST;  // 393216

  hipLaunchKernelGGL(eq_coeffs, dim3((B * K + 63) / 64), dim3(64), 0, stream,
                     fr, gn, qf, cf);
  hipLaunchKernelGGL((eq_pass<false>), dim3(NBC * WPB), dim3(64), 0, stream,
                     audio, cf, nullptr, zsf, out);
  hipLaunchKernelGGL(eq_scan, dim3(NBC), dim3(64), 0, stream, cf, zsf, sif);
  hipLaunchKernelGGL((eq_pass<true>), dim3(NBC * WPB), dim3(64), 0, stream,
                     audio, cf, sif, nullptr, out);
}

// Round 4
// 76.805 us; speedup vs baseline: 2.9240x; 1.7574x over previous
//
#include <hip/hip_runtime.h>
#include <math.h>

namespace {
constexpr int B = 32, C = 2, T = 262144, K = 6;
constexpr int SEG = 1024;         // segments per (b,c)
constexpr int L = T / SEG;        // 256 samples per segment
constexpr int NBC = B * C;        // 64 sequences
constexpr int NST = 2 * K;        // 12-dim cascade state
constexpr int LOG2L = 8;          // L = 2^8
constexpr int GP = SEG / 64;      // 16 segments per scan lane
constexpr int LOG2GP = 4;         // GP = 2^4
constexpr int TS = 16;            // samples per staging tile
constexpr int NT = L / TS;        // 16 tiles
constexpr int WPB = SEG / 64;     // 16 one-wave blocks per (b,c)
constexpr float FS = 44100.0f;
}

__device__ __forceinline__ float rl(float v, int lane) {
  return __int_as_float(__builtin_amdgcn_readlane(__float_as_int(v), lane));
}

// K1: RBJ peaking-EQ coefficients, normalized by a0. cf[(b*K+k)*5 + {b0,b1,b2,a1,a2}]
__global__ void eq_coeffs(const float* __restrict__ fr, const float* __restrict__ gn,
                          const float* __restrict__ qf, float* __restrict__ cf) {
  int i = blockIdx.x * blockDim.x + threadIdx.x;
  if (i >= B * K) return;
  float f = fr[i], g = gn[i], Q = qf[i];
  float A  = powf(10.0f, g * (1.0f / 40.0f));
  float w0 = 6.283185307179586f * f / FS;
  float cw = cosf(w0);
  float al = sinf(w0) / (2.0f * Q);
  float b0 = 1.0f + al * A;
  float b1 = -2.0f * cw;
  float b2 = 1.0f - al * A;
  float a0 = 1.0f + al / A;
  float a2 = 1.0f - al / A;
  float ia = 1.0f / a0;
  float* p = cf + i * 5;
  p[0] = b0 * ia; p[1] = b1 * ia; p[2] = b2 * ia; p[3] = b1 * ia; p[4] = a2 * ia;
}

// Segment pass, 1 wave per block, LDS transpose-staged I/O, depth-2 prefetch.
template <bool WRITE_OUT>
__global__ __launch_bounds__(64, 1) void eq_pass(const float* __restrict__ x,
                                                 const float* __restrict__ cf,
                                                 const float* __restrict__ st_in,
                                                 float* __restrict__ st_out,
                                                 float* __restrict__ y) {
  __shared__ float sIn[2][64][17];
  __shared__ float sOut[2][64][17];

  int l = threadIdx.x;
  int wid = blockIdx.x;           // 0 .. NBC*WPB-1
  int bc = wid / WPB;
  int segbase = (wid % WPB) * 64;
  int b = bc / C;
  int tid = bc * SEG + segbase + l;

  float b0[K], b1[K], b2[K], a1[K], a2[K];
#pragma unroll
  for (int k = 0; k < K; ++k) {
    const float* p = cf + (b * K + k) * 5;
    b0[k] = p[0]; b1[k] = p[1]; b2[k] = p[2]; a1[k] = p[3]; a2[k] = p[4];
  }

  float s1[K], s2[K];
  if (WRITE_OUT) {
    const float4* si = reinterpret_cast<const float4*>(st_in + (size_t)tid * NST);
    float4 v0 = si[0], v1 = si[1], v2 = si[2];
    s1[0] = v0.x; s2[0] = v0.y; s1[1] = v0.z; s2[1] = v0.w;
    s1[2] = v1.x; s2[2] = v1.y; s1[3] = v1.z; s2[3] = v1.w;
    s1[4] = v2.x; s2[4] = v2.y; s1[5] = v2.z; s2[5] = v2.w;
  } else {
#pragma unroll
    for (int k = 0; k < K; ++k) { s1[k] = 0.0f; s2[k] = 0.0f; }
  }

  const float4* xp4 = reinterpret_cast<const float4*>(x + (size_t)bc * T + (size_t)segbase * L);
  float4* yp4 = reinterpret_cast<float4*>(y + (size_t)bc * T + (size_t)segbase * L);
  constexpr int Q4 = L / 4;  // 64 float4 per segment

  int sj = l >> 2;   // staging sub-segment 0..15
  int qj = l & 3;    // 16B quarter of the 64B line

  // prologue: tiles 0 and 1 in flight (two named banks, all static indexing)
  float4 ra[4], rb[4];
#pragma unroll
  for (int j = 0; j < 4; ++j) ra[j] = xp4[(size_t)(j * 16 + sj) * Q4 + qj];
#pragma unroll
  for (int j = 0; j < 4; ++j) rb[j] = xp4[(size_t)(j * 16 + sj) * Q4 + 4 + qj];

  auto tile = [&](float4 (&r)[4], int t, int pb) {
    // stage tile t (regs -> LDS, transposed)
#pragma unroll
    for (int j = 0; j < 4; ++j) {
      int seg = j * 16 + sj;
      sIn[pb][seg][qj * 4 + 0] = r[j].x;
      sIn[pb][seg][qj * 4 + 1] = r[j].y;
      sIn[pb][seg][qj * 4 + 2] = r[j].z;
      sIn[pb][seg][qj * 4 + 3] = r[j].w;
    }
    // issue loads for tile t+2 (land during ~2 tiles of compute)
    if (t + 2 < NT) {
#pragma unroll
      for (int j = 0; j < 4; ++j)
        r[j] = xp4[(size_t)(j * 16 + sj) * Q4 + (size_t)(t + 2) * 4 + qj];
    }
    // own segment: 16 sequential samples through the 6-stage cascade
    float out16[TS];
#pragma unroll
    for (int i = 0; i < TS; ++i) {
      float yv = sIn[pb][l][i];
#pragma unroll
      for (int k = 0; k < K; ++k) {
        float yk = fmaf(b0[k], yv, s1[k]);
        float t1 = fmaf(b1[k], yv, s2[k]);
        s1[k] = fmaf(-a1[k], yk, t1);
        float t2 = b2[k] * yv;
        s2[k] = fmaf(-a2[k], yk, t2);
        yv = yk;
      }
      out16[i] = yv;
    }
    if (WRITE_OUT) {
#pragma unroll
      for (int i = 0; i < TS; ++i) sOut[pb][l][i] = out16[i];
      // flush as full 64B lines
#pragma unroll
      for (int j = 0; j < 4; ++j) {
        int seg = j * 16 + sj;
        float4 o;
        o.x = sOut[pb][seg][qj * 4 + 0];
        o.y = sOut[pb][seg][qj * 4 + 1];
        o.z = sOut[pb][seg][qj * 4 + 2];
        o.w = sOut[pb][seg][qj * 4 + 3];
        yp4[(size_t)seg * Q4 + (size_t)t * 4 + qj] = o;
      }
    }
  };

  for (int tt = 0; tt < NT; tt += 2) {
    tile(ra, tt, 0);
    tile(rb, tt + 1, 1);
  }

  if (!WRITE_OUT) {
    float4* so = reinterpret_cast<float4*>(st_out + (size_t)tid * NST);
    so[0] = make_float4(s1[0], s2[0], s1[1], s2[1]);
    so[1] = make_float4(s1[2], s2[2], s1[3], s2[3]);
    so[2] = make_float4(s1[4], s2[4], s1[5], s2[5]);
  }
}

// K3: 3-level scan. Phase A: squarings give Phi=A^L (stored to LDS) and
// Phi^GP (row form). Phase B: every lane accumulates its GP-segment group's
// zero-state final with Phi replicated in VGPRs. Phase C: 64-step serial scan
// over groups (register-resident, readlane). Phase D: parallel replay writes
// per-segment incoming states.
__global__ __launch_bounds__(64, 1) void eq_scan(const float* __restrict__ cf,
                                                 const float* __restrict__ zsf,
                                                 float* __restrict__ sif) {
  __shared__ float PhiL[NST][NST];      // Phi = A^L, [row][col]
  __shared__ float Mx[NST][NST + 1];    // transpose scratch for Phi^GP
  __shared__ float W[64][NST + 1];      // per-group zero-state finals
  __shared__ float SL[64][NST + 1];     // per-group incoming states

  int bc = blockIdx.x;
  int b = bc / C;
  int l = threadIdx.x;
  bool act = (l < NST);

  float b0[K], b1[K], b2[K], a1[K], a2[K];
#pragma unroll
  for (int k = 0; k < K; ++k) {
    const float* p = cf + (b * K + k) * 5;
    b0[k] = p[0]; b1[k] = p[1]; b2[k] = p[2]; a1[k] = p[3]; a2[k] = p[4];
  }

  // column l of the one-sample homogeneous map A
  float col[NST];
  {
    float s1[K], s2[K];
#pragma unroll
    for (int k = 0; k < K; ++k) {
      s1[k] = (l == 2 * k) ? 1.0f : 0.0f;
      s2[k] = (l == 2 * k + 1) ? 1.0f : 0.0f;
    }
    float yv = 0.0f;
#pragma unroll
    for (int k = 0; k < K; ++k) {
      float yk = fmaf(b0[k], yv, s1[k]);
      float t1 = fmaf(b1[k], yv, s2[k]);
      float ns1 = fmaf(-a1[k], yk, t1);
      float ns2 = fmaf(-a2[k], yk, b2[k] * yv);
      s1[k] = ns1; s2[k] = ns2; yv = yk;
    }
#pragma unroll
    for (int k = 0; k < K; ++k) { col[2 * k] = s1[k]; col[2 * k + 1] = s2[k]; }
  }

  // Phi = A^(2^LOG2L); lane l holds column l
  for (int p = 0; p < LOG2L; ++p) {
    float nc[NST];
#pragma unroll
    for (int r = 0; r < NST; ++r) nc[r] = 0.0f;
#pragma unroll
    for (int m = 0; m < NST; ++m) {
      float w = col[m];
#pragma unroll
      for (int r = 0; r < NST; ++r) nc[r] = fmaf(rl(col[r], m), w, nc[r]);
    }
#pragma unroll
    for (int r = 0; r < NST; ++r) col[r] = nc[r];
  }
  if (act) {
#pragma unroll
    for (int r = 0; r < NST; ++r) PhiL[r][l] = col[r];
  }
  __syncthreads();

  // continue to Phi^GP = A^(2^(LOG2L+LOG2GP))
  for (int p = 0; p < LOG2GP; ++p) {
    float nc[NST];
#pragma unroll
    for (int r = 0; r < NST; ++r) nc[r] = 0.0f;
#pragma unroll
    for (int m = 0; m < NST; ++m) {
      float w = col[m];
#pragma unroll
      for (int r = 0; r < NST; ++r) nc[r] = fmaf(rl(col[r], m), w, nc[r]);
    }
#pragma unroll
    for (int r = 0; r < NST; ++r) col[r] = nc[r];
  }
  if (act) {
#pragma unroll
    for (int r = 0; r < NST; ++r) Mx[r][l] = col[r];
  }
  __syncthreads();
  float row[NST];
#pragma unroll
  for (int m = 0; m < NST; ++m) row[m] = act ? Mx[l][m] : 0.0f;

  // replicate Phi into every lane's registers (broadcast LDS reads)
  float phi[NST][NST];
#pragma unroll
  for (int r = 0; r < NST; ++r)
#pragma unroll
    for (int m = 0; m < NST; ++m) phi[r][m] = PhiL[r][m];

  // Phase B: lane g accumulates zero-state final over its GP segments
  const float* zb = zsf + ((size_t)bc * SEG + (size_t)l * GP) * NST;
  float s[NST];
#pragma unroll
  for (int r = 0; r < NST; ++r) s[r] = 0.0f;
  {
    float zc[NST], zn[NST];
    const float4* zp = reinterpret_cast<const float4*>(zb);
    float4 v0 = zp[0], v1 = zp[1], v2 = zp[2];
    zc[0] = v0.x; zc[1] = v0.y; zc[2] = v0.z; zc[3] = v0.w;
    zc[4] = v1.x; zc[5] = v1.y; zc[6] = v1.z; zc[7] = v1.w;
    zc[8] = v2.x; zc[9] = v2.y; zc[10] = v2.z; zc[11] = v2.w;
    for (int j = 0; j < GP; ++j) {
      if (j + 1 < GP) {
        const float4* zq = reinterpret_cast<const float4*>(zb + (size_t)(j + 1) * NST);
        float4 w0 = zq[0], w1 = zq[1], w2 = zq[2];
        zn[0] = w0.x; zn[1] = w0.y; zn[2] = w0.z; zn[3] = w0.w;
        zn[4] = w1.x; zn[5] = w1.y; zn[6] = w1.z; zn[7] = w1.w;
        zn[8] = w2.x; zn[9] = w2.y; zn[10] = w2.z; zn[11] = w2.w;
      }
      float ns[NST];
#pragma unroll
      for (int r = 0; r < NST; ++r) {
        float a = zc[r];
#pragma unroll
        for (int m = 0; m < NST; ++m) a = fmaf(phi[r][m], s[m], a);
        ns[r] = a;
      }
#pragma unroll
      for (int r = 0; r < NST; ++r) s[r] = ns[r];
#pragma unroll
      for (int r = 0; r < NST; ++r) zc[r] = zn[r];
    }
  }
#pragma unroll
  for (int r = 0; r < NST; ++r) W[l][r] = s[r];
  __syncthreads();

  // Phase C: 64-step serial scan over groups; lane r carries component r
  {
    float sv = 0.0f;
    for (int i = 0; i < 64; ++i) {
      if (act) SL[i][l] = sv;          // incoming state of group i
      float wv = act ? W[i][l] : 0.0f;
      float t0 = fmaf(row[0], rl(sv, 0), fmaf(row[1], rl(sv, 1), row[2] * rl(sv, 2)));
      float t1 = fmaf(row[3], rl(sv, 3), fmaf(row[4], rl(sv, 4), row[5] * rl(sv, 5)));
      float t2 = fmaf(row[6], rl(sv, 6), fmaf(row[7], rl(sv, 7), row[8] * rl(sv, 8)));
      float t3 = fmaf(row[9], rl(sv, 9), fmaf(row[10], rl(sv, 10), row[11] * rl(sv, 11)));
      sv = ((t0 + t1) + (t2 + t3)) + wv;
    }
  }
  __syncthreads();

  // Phase D: replay — lane g emits incoming state of each of its segments
  float sg[NST];
#pragma unroll
  for (int r = 0; r < NST; ++r) sg[r] = SL[l][r];
  {
    float zc[NST], zn[NST];
    const float4* zp = reinterpret_cast<const float4*>(zb);
    float4 v0 = zp[0], v1 = zp[1], v2 = zp[2];
    zc[0] = v0.x; zc[1] = v0.y; zc[2] = v0.z; zc[3] = v0.w;
    zc[4] = v1.x; zc[5] = v1.y; zc[6] = v1.z; zc[7] = v1.w;
    zc[8] = v2.x; zc[9] = v2.y; zc[10] = v2.z; zc[11] = v2.w;
    float* ob = sif + ((size_t)bc * SEG + (size_t)l * GP) * NST;
    for (int j = 0; j < GP; ++j) {
      if (j + 1 < GP) {
        const float4* zq = reinterpret_cast<const float4*>(zb + (size_t)(j + 1) * NST);
        float4 w0 = zq[0], w1 = zq[1], w2 = zq[2];
        zn[0] = w0.x; zn[1] = w0.y; zn[2] = w0.z; zn[3] = w0.w;
        zn[4] = w1.x; zn[5] = w1.y; zn[6] = w1.z; zn[7] = w1.w;
        zn[8] = w2.x; zn[9] = w2.y; zn[10] = w2.z; zn[11] = w2.w;
      }
      float4* op = reinterpret_cast<float4*>(ob + (size_t)j * NST);
      op[0] = make_float4(sg[0], sg[1], sg[2], sg[3]);
      op[1] = make_float4(sg[4], sg[5], sg[6], sg[7]);
      op[2] = make_float4(sg[8], sg[9], sg[10], sg[11]);
      float ns[NST];
#pragma unroll
      for (int r = 0; r < NST; ++r) {
        float a = zc[r];
#pragma unroll
        for (int m = 0; m < NST; ++m) a = fmaf(phi[r][m], sg[m], a);
        ns[r] = a;
      }
#pragma unroll
      for (int r = 0; r < NST; ++r) sg[r] = ns[r];
#pragma unroll
      for (int r = 0; r < NST; ++r) zc[r] = zn[r];
    }
  }
}

extern "C" void kernel_launch(void* const* d_in, const int* in_sizes, int n_in,
                              void* d_out, int out_size, void* d_ws, size_t ws_size,
                              hipStream_t stream) {
  const float* audio = (const float*)d_in[0];
  const float* fr    = (const float*)d_in[1];
  const float* gn    = (const float*)d_in[2];
  const float* qf    = (const float*)d_in[3];
  float* out = (float*)d_out;

  // ws layout (floats): coeffs | zero-state finals | incoming states
  float* cf  = (float*)d_ws;                    // B*K*5 = 960
  float* zsf = cf + B * K * 5;                  // NBC*SEG*NST = 786432
  float* sif = zsf + (size_t)NBC * SEG * NST;   // 786432

  hipLaunchKernelGGL(eq_coeffs, dim3((B * K + 63) / 64), dim3(64), 0, stream,
                     fr, gn, qf, cf);
  hipLaunchKernelGGL((eq_pass<false>), dim3(NBC * WPB), dim3(64), 0, stream,
                     audio, cf, nullptr, zsf, out);
  hipLaunchKernelGGL(eq_scan, dim3(NBC), dim3(64), 0, stream, cf, zsf, sif);
  hipLaunchKernelGGL((eq_pass<true>), dim3(NBC * WPB), dim3(64), 0, stream,
                     audio, cf, sif, nullptr, out);
}